// Round 12
// baseline (474.314 us; speedup 1.0000x reference)
//
#include <hip/hip_runtime.h>
#include <hip/hip_bf16.h>
#include <math.h>

#define B_ 256
#define I_ 512
#define H_ 512
#define BH (B_*H_)
#define KA 1024          // concat K ([inputs | h0])
#define NSL 16           // column-slices per sample
#define SLC 32           // columns per slice

typedef float f4v  __attribute__((ext_vector_type(4)));
typedef short s8v  __attribute__((ext_vector_type(8)));   // 8 bf16
typedef float f32x4 __attribute__((ext_vector_type(4)));

// ws layout (floats):
// [0, 4*BH)            : pre[g][b][k] gate pre-acts WITH biases
// [4*BH, 4*BH+256)     : eta[b] accumulators (float)
// [4*BH+256, +512)     : cnt[b] counters (int, aliased)
// [4*BH+512, ...)      : bf16 planes Ahi, Alo, Bhi, Blo

#define A_ELEMS (256*1024)
#define B_ELEMS (2048*1024)

// ---------------------------------------------------------------------------
// K-1: zero the cross-block accumulators (ws is poisoned 0xAA).
// ---------------------------------------------------------------------------
__global__ __launch_bounds__(256) void k_init(float* __restrict__ eta,
                                              int* __restrict__ cnt) {
    int t = threadIdx.x;
    eta[t] = 0.f;
    cnt[t] = 0;
}

// ---------------------------------------------------------------------------
// K0: fp32 -> split-bf16 (hi/lo) planes for the gate GEMM (proven R8/R9).
// ---------------------------------------------------------------------------
__global__ __launch_bounds__(256) void k_convert(
    const float* __restrict__ inputs, const float* __restrict__ h0,
    const float* __restrict__ Wxf, const float* __restrict__ Whf,
    const float* __restrict__ Wxi, const float* __restrict__ Whi,
    const float* __restrict__ Wxo, const float* __restrict__ Who,
    const float* __restrict__ Wxc, const float* __restrict__ w,
    ushort* __restrict__ Ahi, ushort* __restrict__ Alo,
    ushort* __restrict__ Bhi, ushort* __restrict__ Blo) {
    const int NTOT = A_ELEMS + B_ELEMS;
    int stride = gridDim.x * blockDim.x;
    for (int f = blockIdx.x * blockDim.x + threadIdx.x; f < NTOT; f += stride) {
        float x; ushort* dhi; ushort* dlo; int idx;
        if (f < A_ELEMS) {
            idx = f;
            int m = f >> 10, k = f & 1023;
            x = (k < 512) ? inputs[m * 512 + k] : h0[m * 512 + (k - 512)];
            dhi = Ahi; dlo = Alo;
        } else {
            idx = f - A_ELEMS;
            int n = idx >> 10, k = idx & 1023;
            int g = n >> 9, ko = n & 511;
            if (k < 512) {
                const float* W = (g == 0) ? Wxf : (g == 1) ? Wxi : (g == 2) ? Wxo : Wxc;
                x = W[ko * 512 + k];
            } else if (g < 3) {
                const float* W = (g == 0) ? Whf : (g == 1) ? Whi : Who;
                x = W[ko * 512 + (k - 512)];
            } else {
                x = w[(size_t)(k - 512) * 512 + ko];   // transpose of w
            }
            dhi = Bhi; dlo = Blo;
        }
        __hip_bfloat16 h = __float2bfloat16(x);
        float hf = __bfloat162float(h);
        __hip_bfloat16 l = __float2bfloat16(x - hf);
        dhi[idx] = *(ushort*)&h;
        dlo[idx] = *(ushort*)&l;
    }
}

// ---------------------------------------------------------------------------
// K1: gate GEMM via split-bf16 MFMA (proven R8/R9). Biases folded into pre.
// ---------------------------------------------------------------------------
__global__ __launch_bounds__(256) void k_mfma_gates(
    const ushort* __restrict__ Ahi, const ushort* __restrict__ Alo,
    const ushort* __restrict__ Bhi, const ushort* __restrict__ Blo,
    const float* __restrict__ bxf, const float* __restrict__ bhf,
    const float* __restrict__ bxi, const float* __restrict__ bhi,
    const float* __restrict__ bxo, const float* __restrict__ bho,
    const float* __restrict__ bxc,
    float* __restrict__ pre) {
    int wave = threadIdx.x >> 6, lane = threadIdx.x & 63;
    int tile = blockIdx.x * 4 + wave;        // 0..2047
    int m0 = (tile & 15) << 4;
    int n0 = (tile >> 4) << 4;
    int r  = lane & 15;
    int kg = lane >> 4;

    const s8v* pa_hi = (const s8v*)(Ahi + (size_t)(m0 + r) * KA + kg * 8);
    const s8v* pa_lo = (const s8v*)(Alo + (size_t)(m0 + r) * KA + kg * 8);
    const s8v* pb_hi = (const s8v*)(Bhi + (size_t)(n0 + r) * KA + kg * 8);
    const s8v* pb_lo = (const s8v*)(Blo + (size_t)(n0 + r) * KA + kg * 8);

    f32x4 acc = {0.f, 0.f, 0.f, 0.f};
    #pragma unroll 4
    for (int kc = 0; kc < 32; ++kc) {
        s8v ah = pa_hi[kc * 4];
        s8v al = pa_lo[kc * 4];
        s8v bh = pb_hi[kc * 4];
        s8v bl = pb_lo[kc * 4];
        acc = __builtin_amdgcn_mfma_f32_16x16x32_bf16(ah, bh, acc, 0, 0, 0);
        acc = __builtin_amdgcn_mfma_f32_16x16x32_bf16(ah, bl, acc, 0, 0, 0);
        acc = __builtin_amdgcn_mfma_f32_16x16x32_bf16(al, bh, acc, 0, 0, 0);
    }

    int g  = n0 >> 9;
    int ko = (n0 & 511) + r;
    float bias;
    if (g == 0)      bias = bxf[ko] + bhf[ko];
    else if (g == 1) bias = bxi[ko] + bhi[ko];
    else if (g == 2) bias = bxo[ko] + bho[ko];
    else             bias = bxc[ko];
    #pragma unroll
    for (int j = 0; j < 4; ++j) {
        int m = m0 + kg * 4 + j;
        pre[(size_t)g * BH + (size_t)m * H_ + ko] = acc[j] + bias;
    }
}

// ---------------------------------------------------------------------------
// K2: fused dot+finalize+update. Block = (b, 32-col slice). hebb read ONCE.
// Pass A: NT-load slice, dot in regs, stage bf16 in LDS.
// Exchange: myeta partial via device atomics + spin (16 blocks per b).
// Pass B: update from LDS, NT full-line stores.
// ---------------------------------------------------------------------------
__global__ __launch_bounds__(256) void k_fused(
    const float* __restrict__ hebb, const float* __restrict__ h0,
    const float* __restrict__ pre, const float* __restrict__ c0in,
    const float* __restrict__ alpha,
    const float* __restrict__ Wmod, const float* __restrict__ bmod,
    const float* __restrict__ Wfan, const float* __restrict__ bfan,
    float* __restrict__ eta, int* __restrict__ cnt,
    float* __restrict__ out) {

    __shared__ ushort sh[512][SLC];            // 32 KB bf16 staged slice
    __shared__ float  h0s[512];                // 2 KB
    __shared__ f4v    red[256];                // 4 KB
    __shared__ float  vsh[SLC] __attribute__((aligned(16)));
    __shared__ float  myeta_sh;

    int bid = blockIdx.x;
    int b   = bid >> 4;          // 16 contiguous blocks per sample
    int sl  = bid & 15;
    int c0  = sl * SLC;
    int t   = threadIdx.x;

    h0s[t]       = h0[(size_t)b * H_ + t];
    h0s[t + 256] = h0[(size_t)b * H_ + t + 256];
    __syncthreads();

    int r0 = t >> 3;             // 0..31 (row group)
    int q  = t & 7;              // float4 quad within the 32 cols
    const float* gbase = hebb + ((size_t)b * H_) * H_ + c0 + q * 4;

    // ---- pass A: NT read + dot + bf16 stage ----
    f4v acc = {0.f, 0.f, 0.f, 0.f};
    #pragma unroll
    for (int s = 0; s < 16; ++s) {
        int row = r0 + 32 * s;
        f4v v = __builtin_nontemporal_load((const f4v*)(gbase + (size_t)row * H_));
        acc += h0s[row] * v;
        ushort4 u;
        __hip_bfloat16 b0 = __float2bfloat16(v.x); u.x = *(ushort*)&b0;
        __hip_bfloat16 b1 = __float2bfloat16(v.y); u.y = *(ushort*)&b1;
        __hip_bfloat16 b2 = __float2bfloat16(v.z); u.z = *(ushort*)&b2;
        __hip_bfloat16 b3 = __float2bfloat16(v.w); u.w = *(ushort*)&b3;
        *(ushort4*)&sh[row][q * 4] = u;
    }
    red[t] = acc;
    __syncthreads();
    if (t < 128) red[t] += red[t + 128];  __syncthreads();
    if (t <  64) red[t] += red[t +  64];  __syncthreads();
    if (t <  32) red[t] += red[t +  32];  __syncthreads();
    if (t <  16) red[t] += red[t +  16];  __syncthreads();
    if (t <   8) red[t] += red[t +   8];  __syncthreads();
    // red[q][j] = dot for col c0 + q*4 + j

    // ---- finalize own 32 cols ----
    int col = c0 + (t & 31);
    float ep = 0.f, c2v = 0.f;
    if (t < 32) {
        float dot = red[t >> 2][t & 3];
        size_t off = (size_t)b * H_ + col;
        float pf = pre[0 * BH + off];
        float pi = pre[1 * BH + off];
        float po = pre[2 * BH + off];
        float pc = pre[3 * BH + off];
        float c2 = tanhf(pc + alpha[col] * dot);
        float fg = 1.f / (1.f + expf(-pf));
        float ig = 1.f / (1.f + expf(-pi));
        float og = 1.f / (1.f + expf(-po));
        float cell = fg * c0in[off] + ig * c2;
        float ha = og * tanhf(cell);
        out[off] = ha;                 // hactiv
        out[BH + off] = cell;          // cell
        c2v = c2;
        ep = ha * Wmod[col];
    }
    if (t < 64) {                      // wave-0 reduce (lanes >=32 carry 0)
        #pragma unroll
        for (int o = 32; o > 0; o >>= 1) ep += __shfl_down(ep, o, 64);
        if (t == 0) {
            atomicAdd(&eta[b], ep);
            __hip_atomic_fetch_add(&cnt[b], 1, __ATOMIC_RELEASE,
                                   __HIP_MEMORY_SCOPE_AGENT);
            while (__hip_atomic_load(&cnt[b], __ATOMIC_ACQUIRE,
                                     __HIP_MEMORY_SCOPE_AGENT) < NSL)
                __builtin_amdgcn_s_sleep(2);
            float etot = atomicAdd(&eta[b], 0.0f);   // coherent read
            myeta_sh = tanhf(etot + bmod[0]);
        }
    }
    __syncthreads();
    if (t < 32) vsh[t & 31] = (myeta_sh * Wfan[col] + bfan[col]) * c2v;
    __syncthreads();

    // ---- pass B: update from LDS, NT store ----
    f4v vq = *(const f4v*)&vsh[q * 4];
    float* gout = out + 2 * BH + ((size_t)b * H_) * H_ + c0 + q * 4;
    #pragma unroll
    for (int s = 0; s < 16; ++s) {
        int row = r0 + 32 * s;
        ushort4 u = *(const ushort4*)&sh[row][q * 4];
        f4v hb;
        hb.x = __uint_as_float(((unsigned)u.x) << 16);
        hb.y = __uint_as_float(((unsigned)u.y) << 16);
        hb.z = __uint_as_float(((unsigned)u.z) << 16);
        hb.w = __uint_as_float(((unsigned)u.w) << 16);
        f4v r = hb + h0s[row] * vq;
        r.x = fminf(fmaxf(r.x, -2.f), 2.f);
        r.y = fminf(fmaxf(r.y, -2.f), 2.f);
        r.z = fminf(fmaxf(r.z, -2.f), 2.f);
        r.w = fminf(fmaxf(r.w, -2.f), 2.f);
        __builtin_nontemporal_store(r, (f4v*)(gout + (size_t)row * H_));
    }
}

// ---------------------------------------------------------------------------
extern "C" void kernel_launch(void* const* d_in, const int* in_sizes, int n_in,
                              void* d_out, int out_size, void* d_ws, size_t ws_size,
                              hipStream_t stream) {
    const float* inputs = (const float*)d_in[0];
    const float* h0     = (const float*)d_in[1];
    const float* c0     = (const float*)d_in[2];
    const float* hebb   = (const float*)d_in[3];
    const float* w      = (const float*)d_in[4];
    const float* alpha  = (const float*)d_in[5];
    const float* Wxf = (const float*)d_in[6];  const float* bxf = (const float*)d_in[7];
    const float* Whf = (const float*)d_in[8];  const float* bhf = (const float*)d_in[9];
    const float* Wxi = (const float*)d_in[10]; const float* bxi = (const float*)d_in[11];
    const float* Whi = (const float*)d_in[12]; const float* bhi = (const float*)d_in[13];
    const float* Wxo = (const float*)d_in[14]; const float* bxo = (const float*)d_in[15];
    const float* Who = (const float*)d_in[16]; const float* bho = (const float*)d_in[17];
    const float* Wxc = (const float*)d_in[18]; const float* bxc = (const float*)d_in[19];
    const float* Wmod = (const float*)d_in[20]; const float* bmod = (const float*)d_in[21];
    const float* Wfan = (const float*)d_in[22]; const float* bfan = (const float*)d_in[23];

    float* out = (float*)d_out;
    float* ws  = (float*)d_ws;
    float*  pre  = ws;                        // 4*BH
    float*  eta  = ws + 4 * BH;               // 256 floats
    int*    cnt  = (int*)(ws + 4 * BH + 256); // 256 ints
    ushort* Ahi  = (ushort*)(ws + 4 * BH + 512);
    ushort* Alo  = Ahi + A_ELEMS;
    ushort* Bhi  = Alo + A_ELEMS;
    ushort* Blo  = Bhi + B_ELEMS;

    // -1) zero cross-block accumulators (ws is poisoned)
    k_init<<<1, 256, 0, stream>>>(eta, cnt);
    // 0) split-bf16 conversion
    k_convert<<<2048, 256, 0, stream>>>(inputs, h0,
        Wxf, Whf, Wxi, Whi, Wxo, Who, Wxc, w, Ahi, Alo, Bhi, Blo);
    // 1) gate GEMM on matrix cores (biases folded)
    k_mfma_gates<<<512, 256, 0, stream>>>(Ahi, Alo, Bhi, Blo,
        bxf, bhf, bxi, bhi, bxo, bho, bxc, pre);
    // 2) fused hebbdot + finalize + update: hebb read exactly once
    k_fused<<<B_ * NSL, 256, 0, stream>>>(hebb, h0, pre, c0, alpha,
        Wmod, bmod, Wfan, bfan, eta, cnt, out);
}